// Round 4
// baseline (180.090 us; speedup 1.0000x reference)
//
#include <hip/hip_runtime.h>
#include <math.h>

// Problem constants
#define BATCH 256
#define IC    1152
#define EDIM  8
#define NC    10
#define DV    16

// Tiling
#define ITILE  8                    // i's covered by thread layout (il = 0..7)
#define NCHUNK 4                    // i-chunks looped per block
#define ITOT   (ITILE * NCHUNK)     // 32 i's per block
#define NB     4                    // b's per block (register s-acc = 20 VGPRs)
#define NTHREADS 256                // 256 = 16 d * 2 il_lo * 2 ch * 4 il_hi
#define NWAVES 4
#define NSLAB  (IC / ITOT)          // 36 partial slabs
#define BCHUNKS (BATCH / NB)        // 64
#define SCD (NC * DV)               // 160
#define SPART_STRIDE (BATCH * SCD)  // 40960 floats per slab
#define L2E 1.4426950408889634f
#define B2_BLK (NB * ITOT * 2 * 8)  // 2048 floats of b2 per block

// ---------------------------------------------------------------------------
// DPP-based 16-lane (row) sum reduce — all VALU, no DS pipe.
// MUST stay on __builtin_amdgcn_update_dpp: the compiler inserts the
// mandatory VALU->DPP hazard wait-states. R2's hand-written v_add_f32_dpp
// inline asm skipped them (hazard recognizer doesn't scan asm bodies) and
// silently read stale lanes -> absmax 0.39 FAIL. Do not regress.
// ---------------------------------------------------------------------------
template<int CTRL>
__device__ __forceinline__ float dpp_add(float x) {
    int r = __builtin_amdgcn_update_dpp(0, __float_as_int(x), CTRL, 0xF, 0xF, true);
    return x + __int_as_float(r);
}
__device__ __forceinline__ float row_reduce16(float x) {
    x = dpp_add<0xB1>(x);   // quad_perm [1,0,3,2] : xor 1
    x = dpp_add<0x4E>(x);   // quad_perm [2,3,0,1] : xor 2
    x = dpp_add<0x141>(x);  // row_half_mirror     : xor 4
    x = dpp_add<0x140>(x);  // row_mirror          : xor 8
    return x;
}

// ---------------------------------------------------------------------------
// Cross-half (lane ^ 32) sum, pure VALU on gfx950 (no DS pipe / lgkmcnt).
// r[0]+r[1] == x + partner(x) in every lane. Builtin — HW-verified in R1.
// ---------------------------------------------------------------------------
typedef int int2v __attribute__((ext_vector_type(2)));
#if __has_builtin(__builtin_amdgcn_permlane32_swap)
__device__ __forceinline__ float cross32_sum(float x) {
    int2v r = __builtin_amdgcn_permlane32_swap(__float_as_int(x), __float_as_int(x),
                                               false, false);
    return __int_as_float(r[0]) + __int_as_float(r[1]);
}
#else
__device__ __forceinline__ float cross32_sum(float x) { return x + __shfl_xor(x, 32); }
#endif

#if __has_builtin(__builtin_amdgcn_exp2f)
#define EXP2F(x) __builtin_amdgcn_exp2f(x)
#else
#define EXP2F(x) exp2f(x)
#endif

// ---------------------------------------------------------------------------
// Main fused kernel. LANE MAP: d = bits0-3, il_lo = bit4, ch = bit5,
// il_hi = bits6-7 (== wid). ch at bit5 makes the softmax cross-ch sum a
// v_permlane32_swap (VALU).
//
// STRUCTURE = R0's proven one: slab s-partials written by the epilogue
// (plain stores), reduced+squashed by a separate tiny kernel. R1's
// device-atomic s-accumulation quadrupled HBM writes (per-XCD L2s are not
// coherent; device atomics go to fabric) and stays reverted.
//
// R4: the inner body now touches NO global memory. All per-body operands
// are prologue-staged into LDS behind the one existing barrier:
//   - v tile   (2.5 KB, R3-proven)
//   - bias slice (1.25 KB, contiguous at i0*NC, pre-scaled by log2e)
//   - b2 tile  (8 KB, MODE 3 only) — b2 is now BLOCK-CONTIGUOUS:
//     [icb][bcb][bb][i_local][ch][8]. MODE 2 writes one 8 KB region per
//     block; MODE 3 stages it with 2 coalesced float4 loads per thread.
//     Removes the per-body L3-latency bp loads that sat on the softmax
//     critical path (R3: VALUBusy 62% @ 25% occupancy = latency-stalled).
//
// SPILL HISTORY (do not regress):
//   (256,4)/(256,3) caps spilled; (256,2) cap 256 with NB=4 allocates ~84
//   VGPR, no spill. R1 lesson: do NOT hoist v (or b2) into per-thread
//   register arrays (+20 VGPR -> 5 waves/SIMD, occupancy 26.6->18.0).
//
// NUMERICS: softmax max-pass removed (|logits| <~ 20 << 88; R1/R3-proven).
// 1/sum via v_rcp_f32 (rel err ~1e-7). Routing logits in log2 domain:
// v_in pre-scaled by L2E (caps_squash), bias pre-scaled at staging, so
// softmax exp is raw v_exp_f32 (exp2). b2 stores scaled logits
// (internal-only, consistent between MODE 2 and 3). MODE 1 softmax uses
// the same exp2 path: exp2(L2E*bias) == exp(bias).
//
// MODE 1: c = softmax(bias)                              -> s1 partials
// MODE 2: b2 = L2E*(u.v1) + 2*L2E*bias (stored), softmax -> s2 partials
// MODE 3: b3 = L2E*(u.v2) + b2 + L2E*bias, softmax       -> s3 partials
// ---------------------------------------------------------------------------
template<int MODE>
__global__ __launch_bounds__(NTHREADS, 2)
void caps_main(const float* __restrict__ x,
               const float* __restrict__ W,
               const float* __restrict__ bias,
               const float* __restrict__ v_in,   // pre-scaled by L2E
               float* __restrict__ b2,
               float* __restrict__ s_part)
{
    __shared__ float sx[NB][ITOT * EDIM];    // 4 KB
    __shared__ float swv[NWAVES][NB][SCD];   // 10 KB — wave-private slabs
    __shared__ float vls[NB][SCD];           // 2.5 KB — v tile (MODE != 1)
    __shared__ float bls[ITOT * NC];         // 1.25 KB — L2E*bias slice
    __shared__ float b2ls[B2_BLK];           // 8 KB — b2 tile (MODE == 3)

    const int tid = threadIdx.x;
    const int d   = tid & 15;
    const int ch  = (tid >> 5) & 1;                       // lane bit 5
    const int il  = ((tid >> 4) & 1) | (((tid >> 6) & 3) << 1);
    const int wid = tid >> 6;                // 0..3
    const int icb = blockIdx.x;              // 0..35
    const int bcb = blockIdx.y;              // 0..63
    const int i0  = icb * ITOT;
    const int b0  = bcb * NB;
    const size_t b2_blk_off = (size_t)(icb * BCHUNKS + bcb) * B2_BLK;

    // ---- stage x slice: 256 float4, one per thread, coalesced ----
    {
        const float4* xg = (const float4*)x;
        float4* xs = (float4*)&sx[0][0];
        int bb = tid >> 6;                   // 64 float4 per b row
        int w  = tid & 63;
        xs[tid] = xg[(size_t)(b0 + bb) * (IC * EDIM / 4) + i0 * (EDIM / 4) + w];
    }
    // ---- stage bias slice (contiguous at i0*NC), pre-scaled by L2E ----
    {
        bls[tid] = bias[i0 * NC + tid] * L2E;              // tid < 256
        if (tid < ITOT * NC - NTHREADS)                    // 64 more
            bls[NTHREADS + tid] = bias[i0 * NC + NTHREADS + tid] * L2E;
    }
    // ---- stage v tile (640 floats, coalesced) ----
    if (MODE != 1) {
        #pragma unroll
        for (int t = 0; t < 3; ++t) {
            int j = t * NTHREADS + tid;
            if (j < NB * SCD)
                (&vls[0][0])[j] = v_in[(size_t)b0 * SCD + j];
        }
    }
    // ---- stage b2 tile (2048 floats = 512 float4), MODE 3 only ----
    if (MODE == 3) {
        const float4* bg = (const float4*)(b2 + b2_blk_off);
        float4* bs = (float4*)b2ls;
        bs[tid]            = bg[tid];
        bs[NTHREADS + tid] = bg[NTHREADS + tid];
    }

    float sacc[NB][5];
    #pragma unroll
    for (int bb = 0; bb < NB; ++bb)
        #pragma unroll
        for (int k = 0; k < 5; ++k) sacc[bb][k] = 0.f;

    __syncthreads();

    const float4* Wg = (const float4*)W;

    #pragma unroll 1
    for (int ic = 0; ic < NCHUNK; ++ic) {
        const int ii = ic * ITILE + il;      // i_local
        const int i  = i0 + ii;

        // W fragment for this i-chunk (global, L2-hot) + bias from LDS
        float4 w4[5][2];
        float  bvs[5];
        #pragma unroll
        for (int k = 0; k < 5; ++k) {
            int c = ch * 5 + k;
            size_t base = ((size_t)(i * NC + c) * DV + d) * 2;
            w4[k][0] = Wg[base];
            w4[k][1] = Wg[base + 1];
            bvs[k]   = bls[ii * NC + c];     // already * L2E
        }

        float cw[5];
        if (MODE == 1) {
            // softmax(bias[i,:]) — batch-independent, once per i-chunk.
            // exp2(L2E*bias) == exp(bias).
            float ssum = 0.f, ex[5];
            #pragma unroll
            for (int k = 0; k < 5; ++k) { ex[k] = EXP2F(bvs[k]); ssum += ex[k]; }
            ssum = cross32_sum(ssum);
            float inv = __builtin_amdgcn_rcpf(ssum);
            #pragma unroll
            for (int k = 0; k < 5; ++k) cw[k] = ex[k] * inv;
        }

        #pragma unroll
        for (int bb = 0; bb < NB; ++bb) {
            const float4 x0 = ((const float4*)&sx[bb][ii * EDIM])[0];
            const float4 x1 = ((const float4*)&sx[bb][ii * EDIM])[1];

            // u_hat[b, i, c_k, d]
            float u[5];
            #pragma unroll
            for (int k = 0; k < 5; ++k) {
                float acc = w4[k][0].x * x0.x;
                acc = fmaf(w4[k][0].y, x0.y, acc);
                acc = fmaf(w4[k][0].z, x0.z, acc);
                acc = fmaf(w4[k][0].w, x0.w, acc);
                acc = fmaf(w4[k][1].x, x1.x, acc);
                acc = fmaf(w4[k][1].y, x1.y, acc);
                acc = fmaf(w4[k][1].z, x1.z, acc);
                acc = fmaf(w4[k][1].w, x1.w, acc);
                u[k] = acc;
            }

            if (MODE != 1) {
                // agreement (L2E-scaled via v): sum over d via DPP row reduce
                const float* vb = &vls[bb][ch * 80 + d];
                float t[5];
                #pragma unroll
                for (int k = 0; k < 5; ++k) t[k] = u[k] * vb[k * 16];
                #pragma unroll
                for (int k = 0; k < 5; ++k) t[k] = row_reduce16(t[k]);

                float br[5];
                const int bloc = ((bb * ITOT + ii) * 2 + ch) * 8;
                if (MODE == 2) {
                    #pragma unroll
                    for (int k = 0; k < 5; ++k) br[k] = fmaf(2.0f, bvs[k], t[k]);
                    if (d == 0) {
                        float* bp = b2 + b2_blk_off + bloc;
                        #pragma unroll
                        for (int k = 0; k < 5; ++k) bp[k] = br[k];
                    }
                } else {
                    const float* bp = &b2ls[bloc];     // LDS, prologue-staged
                    #pragma unroll
                    for (int k = 0; k < 5; ++k) br[k] = t[k] + bp[k] + bvs[k];
                }
                // softmax over 10 c's: 5 local + partner half via permlane32.
                // Logits are log2-domain -> raw v_exp_f32, no max-pass.
                float ssum = 0.f, ex[5];
                #pragma unroll
                for (int k = 0; k < 5; ++k) { ex[k] = EXP2F(br[k]); ssum += ex[k]; }
                ssum = cross32_sum(ssum);
                float inv = __builtin_amdgcn_rcpf(ssum);
                #pragma unroll
                for (int k = 0; k < 5; ++k) cw[k] = ex[k] * inv;
            }

            // register s-accumulation — no LDS, no shuffle, no barrier
            #pragma unroll
            for (int k = 0; k < 5; ++k)
                sacc[bb][k] = fmaf(cw[k], u[k], sacc[bb][k]);
        }
    }

    // ---- epilogue: il-pair reduce + wave slabs + 4-way reduce + flush ----
    #pragma unroll
    for (int bb = 0; bb < NB; ++bb) {
        #pragma unroll
        for (int k = 0; k < 5; ++k) {
            float s = sacc[bb][k] + __shfl_xor(sacc[bb][k], 16);
            if ((tid & 16) == 0)
                swv[wid][bb][ch * 80 + k * 16 + d] = s;
        }
    }
    __syncthreads();
    for (int j = tid; j < NB * SCD; j += NTHREADS) {    // 640 elems
        int bb = j / SCD;
        int cd = j - bb * SCD;
        float s = (swv[0][bb][cd] + swv[1][bb][cd])
                + (swv[2][bb][cd] + swv[3][bb][cd]);
        s_part[((size_t)icb * BATCH + b0 + bb) * SCD + cd] = s;
    }
}

// ---------------------------------------------------------------------------
// Reduce s-partials over the 36 slabs and apply squash.
// Block = 16 (b,c) groups x 16 d. Grid = 2560/16 = 160 blocks.
// mult = L2E for intermediate v (log2-domain routing), 1.0 for final out.
// ---------------------------------------------------------------------------
__global__ __launch_bounds__(256)
void caps_squash(const float* __restrict__ s_part, float* __restrict__ out,
                 float mult)
{
    const int tid = threadIdx.x;
    const int bc  = blockIdx.x * 16 + (tid >> 4);
    const size_t off = (size_t)bc * DV + (tid & 15);

    float a[4] = {0.f, 0.f, 0.f, 0.f};
    #pragma unroll
    for (int ic = 0; ic < NSLAB; ic += 4) {
        #pragma unroll
        for (int j = 0; j < 4; ++j)
            a[j] += s_part[(size_t)(ic + j) * SPART_STRIDE + off];
    }
    float s = (a[0] + a[1]) + (a[2] + a[3]);

    float sq = row_reduce16(s * s);

    // scale = sq/(1+sq)/sqrt(sq+EPS), EPS = 1e-7 (matches reference)
    float scale = sq / ((1.0f + sq) * sqrtf(sq + 1e-7f));
    out[off] = (mult * scale) * s;
}

// ---------------------------------------------------------------------------
extern "C" void kernel_launch(void* const* d_in, const int* in_sizes, int n_in,
                              void* d_out, int out_size, void* d_ws, size_t ws_size,
                              hipStream_t stream)
{
    const float* x    = (const float*)d_in[0];   // [256,1152,8]
    const float* W    = (const float*)d_in[1];   // [1152,10,16,8]
    const float* bias = (const float*)d_in[2];   // [1152,10]
    float* out = (float*)d_out;                  // [256,10,16]

    float* ws     = (float*)d_ws;
    float* s_part = ws;                                       // 36*40960 = 1,474,560 f
    float* v      = s_part + (size_t)NSLAB * SPART_STRIDE;    // 40,960 f (L2E-scaled)
    float* b2     = v + SPART_STRIDE;                         // block-contig: 4,718,592 f
    // total ws use: ~25 MB

    dim3 grid(NSLAB, BCHUNKS);   // 36 x 64 = 2304 blocks

    // iter 1
    caps_main<1><<<grid, NTHREADS, 0, stream>>>(x, W, bias, v, b2, s_part);
    caps_squash<<<160, 256, 0, stream>>>(s_part, v, L2E);
    // iter 2
    caps_main<2><<<grid, NTHREADS, 0, stream>>>(x, W, bias, v, b2, s_part);
    caps_squash<<<160, 256, 0, stream>>>(s_part, v, L2E);
    // final
    caps_main<3><<<grid, NTHREADS, 0, stream>>>(x, W, bias, v, b2, s_part);
    caps_squash<<<160, 256, 0, stream>>>(s_part, out, 1.0f);
}

// Round 5
// 174.194 us; speedup vs baseline: 1.0339x; 1.0339x over previous
//
#include <hip/hip_runtime.h>
#include <math.h>

// Problem constants
#define BATCH 256
#define IC    1152
#define EDIM  8
#define NC    10
#define DV    16

// Tiling
#define ITILE  8                    // i's covered by thread layout (il = 0..7)
#define NCHUNK 4                    // i-chunks looped per block
#define ITOT   (ITILE * NCHUNK)     // 32 i's per block
#define NB     4                    // b's per block (register s-acc = 20 VGPRs)
#define NTHREADS 256                // 256 = 16 d * 2 il_lo * 2 ch * 4 il_hi
#define NWAVES 4
#define NSLAB  (IC / ITOT)          // 36 partial slabs
#define BCHUNKS (BATCH / NB)        // 64
#define SCD (NC * DV)               // 160
#define SPART_STRIDE (BATCH * SCD)  // 40960 floats per slab
#define L2E 1.4426950408889634f

// ---------------------------------------------------------------------------
// DPP-based 16-lane (row) sum reduce — all VALU, no DS pipe.
// MUST stay on __builtin_amdgcn_update_dpp: the compiler inserts the
// mandatory VALU->DPP hazard wait-states. R2's hand-written v_add_f32_dpp
// inline asm skipped them (hazard recognizer doesn't scan asm bodies) and
// silently read stale lanes -> absmax 0.39 FAIL. Do not regress.
// ---------------------------------------------------------------------------
template<int CTRL>
__device__ __forceinline__ float dpp_add(float x) {
    int r = __builtin_amdgcn_update_dpp(0, __float_as_int(x), CTRL, 0xF, 0xF, true);
    return x + __int_as_float(r);
}
__device__ __forceinline__ float row_reduce16(float x) {
    x = dpp_add<0xB1>(x);   // quad_perm [1,0,3,2] : xor 1
    x = dpp_add<0x4E>(x);   // quad_perm [2,3,0,1] : xor 2
    x = dpp_add<0x141>(x);  // row_half_mirror     : xor 4
    x = dpp_add<0x140>(x);  // row_mirror          : xor 8
    return x;
}

// ---------------------------------------------------------------------------
// Cross-half (lane ^ 32) sum, pure VALU on gfx950 (no DS pipe / lgkmcnt).
// r[0]+r[1] == x + partner(x) in every lane. Builtin — HW-verified in R1.
// ---------------------------------------------------------------------------
typedef int int2v __attribute__((ext_vector_type(2)));
#if __has_builtin(__builtin_amdgcn_permlane32_swap)
__device__ __forceinline__ float cross32_sum(float x) {
    int2v r = __builtin_amdgcn_permlane32_swap(__float_as_int(x), __float_as_int(x),
                                               false, false);
    return __int_as_float(r[0]) + __int_as_float(r[1]);
}
#else
__device__ __forceinline__ float cross32_sum(float x) { return x + __shfl_xor(x, 32); }
#endif

#if __has_builtin(__builtin_amdgcn_exp2f)
#define EXP2F(x) __builtin_amdgcn_exp2f(x)
#else
#define EXP2F(x) exp2f(x)
#endif

// ---------------------------------------------------------------------------
// Main fused kernel. LANE MAP: d = bits0-3, il_lo = bit4, ch = bit5,
// il_hi = bits6-7 (== wid). ch at bit5 makes the softmax cross-ch sum a
// v_permlane32_swap (VALU).
//
// STRUCTURE = R3's proven one (169.6 us): slab s-partials written by the
// epilogue (plain stores), reduced+squashed by a separate tiny kernel;
// v staged to LDS in the prologue; bias + b2 accessed from global in the
// body (R4's LDS staging of those pushed VGPR 84->88, crossing the
// 6->5 waves/SIMD boundary: occupancy 25->18.5%, +10us. REVERTED).
//
// R5 change (register-neutral): GRID ORDER SWIZZLE. W has no intra-block
// reuse but 64x cross-block reuse per icb (164 KB slice shared by all
// bcb-blocks). Old grid(icb,bcb) -> consecutive linear block ids span all
// 36 icb's, so each XCD's ~64 resident blocks touch ~all 5.9 MB of W,
// thrashing its 4 MB L2 -> W loads at L3 latency on the chunk critical
// path. New grid(bcb,icb): 64 consecutive ids share one icb -> per-XCD
// concurrent W working set = one 164 KB slice -> L2-hit latency.
//
// SPILL/VGPR HISTORY (do not regress):
//   (256,4)/(256,3) caps spilled; (256,2) cap 256 with NB=4 allocates 84
//   VGPR = 6 waves/SIMD. 85..102 VGPR drops to 5 waves (R4: -17% TLP).
//   Do NOT hoist v/b2/bias into registers or add prologue staging arrays.
//
// NUMERICS: softmax max-pass removed (|logits| <~ 20 << 88; R1/R3-proven).
// 1/sum via v_rcp_f32 (rel err ~1e-7). Routing logits in log2 domain:
// v_in pre-scaled by L2E (caps_squash writes it), bias scaled once per
// i-chunk, so softmax exp is raw v_exp_f32 (exp2). b2 stores scaled
// logits (internal-only buffer, consistent between MODE 2 and 3).
//
// MODE 1: c = softmax(bias)                              -> s1 partials
// MODE 2: b2 = L2E*(u.v1) + 2*L2E*bias (stored), softmax -> s2 partials
// MODE 3: b3 = L2E*(u.v2) + b2 + L2E*bias, softmax       -> s3 partials
// ---------------------------------------------------------------------------
template<int MODE>
__global__ __launch_bounds__(NTHREADS, 2)
void caps_main(const float* __restrict__ x,
               const float* __restrict__ W,
               const float* __restrict__ bias,
               const float* __restrict__ v_in,   // pre-scaled by L2E
               float* __restrict__ b2,
               float* __restrict__ s_part)
{
    __shared__ float sx[NB][ITOT * EDIM];    // 4 KB
    __shared__ float swv[NWAVES][NB][SCD];   // 10 KB — wave-private slabs
    __shared__ float vls[NB][SCD];           // 2.5 KB — v tile (MODE != 1)

    const int tid = threadIdx.x;
    const int d   = tid & 15;
    const int ch  = (tid >> 5) & 1;                       // lane bit 5
    const int il  = ((tid >> 4) & 1) | (((tid >> 6) & 3) << 1);
    const int wid = tid >> 6;                // 0..3
    const int bcb = blockIdx.x;              // 0..63  (fast axis: shares icb)
    const int icb = blockIdx.y;              // 0..35
    const int i0  = icb * ITOT;
    const int b0  = bcb * NB;

    // ---- stage x slice: 256 float4, one per thread, coalesced ----
    {
        const float4* xg = (const float4*)x;
        float4* xs = (float4*)&sx[0][0];
        int bb = tid >> 6;                   // 64 float4 per b row
        int w  = tid & 63;
        xs[tid] = xg[(size_t)(b0 + bb) * (IC * EDIM / 4) + i0 * (EDIM / 4) + w];
    }
    // ---- stage v tile (640 floats, coalesced) ----
    if (MODE != 1) {
        #pragma unroll
        for (int t = 0; t < 3; ++t) {
            int j = t * NTHREADS + tid;
            if (j < NB * SCD)
                (&vls[0][0])[j] = v_in[(size_t)b0 * SCD + j];
        }
    }

    float sacc[NB][5];
    #pragma unroll
    for (int bb = 0; bb < NB; ++bb)
        #pragma unroll
        for (int k = 0; k < 5; ++k) sacc[bb][k] = 0.f;

    __syncthreads();

    const float4* Wg = (const float4*)W;

    #pragma unroll 1
    for (int ic = 0; ic < NCHUNK; ++ic) {
        const int i = i0 + ic * ITILE + il;

        // W fragment + bias for this i-chunk
        float4 w4[5][2];
        float  bv[5];
        #pragma unroll
        for (int k = 0; k < 5; ++k) {
            int c = ch * 5 + k;
            size_t base = ((size_t)(i * NC + c) * DV + d) * 2;
            w4[k][0] = Wg[base];
            w4[k][1] = Wg[base + 1];
            bv[k]    = bias[i * NC + c];
        }

        float cw[5];
        float bvs[5];
        if (MODE == 1) {
            // softmax(bias[i,:]) — batch-independent, once per i-chunk
            float ssum = 0.f, ex[5];
            #pragma unroll
            for (int k = 0; k < 5; ++k) { ex[k] = __expf(bv[k]); ssum += ex[k]; }
            ssum = cross32_sum(ssum);
            float inv = __builtin_amdgcn_rcpf(ssum);
            #pragma unroll
            for (int k = 0; k < 5; ++k) cw[k] = ex[k] * inv;
        } else {
            #pragma unroll
            for (int k = 0; k < 5; ++k) bvs[k] = bv[k] * L2E;
        }

        #pragma unroll
        for (int bb = 0; bb < NB; ++bb) {
            const int b = b0 + bb;
            const float4 x0 = ((const float4*)&sx[bb][(ic * ITILE + il) * EDIM])[0];
            const float4 x1 = ((const float4*)&sx[bb][(ic * ITILE + il) * EDIM])[1];

            // u_hat[b, i, c_k, d]
            float u[5];
            #pragma unroll
            for (int k = 0; k < 5; ++k) {
                float acc = w4[k][0].x * x0.x;
                acc = fmaf(w4[k][0].y, x0.y, acc);
                acc = fmaf(w4[k][0].z, x0.z, acc);
                acc = fmaf(w4[k][0].w, x0.w, acc);
                acc = fmaf(w4[k][1].x, x1.x, acc);
                acc = fmaf(w4[k][1].y, x1.y, acc);
                acc = fmaf(w4[k][1].z, x1.z, acc);
                acc = fmaf(w4[k][1].w, x1.w, acc);
                u[k] = acc;
            }

            if (MODE != 1) {
                // agreement (L2E-scaled via v): sum over d via DPP row reduce
                const float* vb = &vls[bb][ch * 80 + d];
                float t[5];
                #pragma unroll
                for (int k = 0; k < 5; ++k) t[k] = u[k] * vb[k * 16];
                #pragma unroll
                for (int k = 0; k < 5; ++k) t[k] = row_reduce16(t[k]);

                float br[5];
                float* bp = b2 + (((size_t)b * IC + i) * 2 + ch) * 8;  // padded
                if (MODE == 2) {
                    #pragma unroll
                    for (int k = 0; k < 5; ++k) br[k] = fmaf(2.0f, bvs[k], t[k]);
                    if (d == 0) {
                        #pragma unroll
                        for (int k = 0; k < 5; ++k) bp[k] = br[k];
                    }
                } else {
                    #pragma unroll
                    for (int k = 0; k < 5; ++k) br[k] = t[k] + bp[k] + bvs[k];
                }
                // softmax over 10 c's: 5 local + partner half via permlane32.
                // Logits are log2-domain -> raw v_exp_f32, no max-pass.
                float ssum = 0.f, ex[5];
                #pragma unroll
                for (int k = 0; k < 5; ++k) { ex[k] = EXP2F(br[k]); ssum += ex[k]; }
                ssum = cross32_sum(ssum);
                float inv = __builtin_amdgcn_rcpf(ssum);
                #pragma unroll
                for (int k = 0; k < 5; ++k) cw[k] = ex[k] * inv;
            }

            // register s-accumulation — no LDS, no shuffle, no barrier
            #pragma unroll
            for (int k = 0; k < 5; ++k)
                sacc[bb][k] = fmaf(cw[k], u[k], sacc[bb][k]);
        }
    }

    // ---- epilogue: il-pair reduce + wave slabs + 4-way reduce + flush ----
    #pragma unroll
    for (int bb = 0; bb < NB; ++bb) {
        #pragma unroll
        for (int k = 0; k < 5; ++k) {
            float s = sacc[bb][k] + __shfl_xor(sacc[bb][k], 16);
            if ((tid & 16) == 0)
                swv[wid][bb][ch * 80 + k * 16 + d] = s;
        }
    }
    __syncthreads();
    for (int j = tid; j < NB * SCD; j += NTHREADS) {    // 640 elems
        int bb = j / SCD;
        int cd = j - bb * SCD;
        float s = (swv[0][bb][cd] + swv[1][bb][cd])
                + (swv[2][bb][cd] + swv[3][bb][cd]);
        s_part[((size_t)icb * BATCH + b0 + bb) * SCD + cd] = s;
    }
}

// ---------------------------------------------------------------------------
// Reduce s-partials over the 36 slabs and apply squash.
// Block = 16 (b,c) groups x 16 d. Grid = 2560/16 = 160 blocks.
// mult = L2E for intermediate v (log2-domain routing), 1.0 for final out.
// ---------------------------------------------------------------------------
__global__ __launch_bounds__(256)
void caps_squash(const float* __restrict__ s_part, float* __restrict__ out,
                 float mult)
{
    const int tid = threadIdx.x;
    const int bc  = blockIdx.x * 16 + (tid >> 4);
    const size_t off = (size_t)bc * DV + (tid & 15);

    float a[4] = {0.f, 0.f, 0.f, 0.f};
    #pragma unroll
    for (int ic = 0; ic < NSLAB; ic += 4) {
        #pragma unroll
        for (int j = 0; j < 4; ++j)
            a[j] += s_part[(size_t)(ic + j) * SPART_STRIDE + off];
    }
    float s = (a[0] + a[1]) + (a[2] + a[3]);

    float sq = row_reduce16(s * s);

    // scale = sq/(1+sq)/sqrt(sq+EPS), EPS = 1e-7 (matches reference)
    float scale = sq / ((1.0f + sq) * sqrtf(sq + 1e-7f));
    out[off] = (mult * scale) * s;
}

// ---------------------------------------------------------------------------
extern "C" void kernel_launch(void* const* d_in, const int* in_sizes, int n_in,
                              void* d_out, int out_size, void* d_ws, size_t ws_size,
                              hipStream_t stream)
{
    const float* x    = (const float*)d_in[0];   // [256,1152,8]
    const float* W    = (const float*)d_in[1];   // [1152,10,16,8]
    const float* bias = (const float*)d_in[2];   // [1152,10]
    float* out = (float*)d_out;                  // [256,10,16]

    float* ws     = (float*)d_ws;
    float* s_part = ws;                                       // 36*40960 = 1,474,560 f
    float* v      = s_part + (size_t)NSLAB * SPART_STRIDE;    // 40,960 f (L2E-scaled)
    float* b2     = v + SPART_STRIDE;                         // padded: 4,718,592 f
    // total ws use: ~25 MB

    // bcb on the FAST grid axis: consecutive linear block ids share icb
    // (same 164 KB W slice) -> concurrent L2 reuse per XCD (see header).
    dim3 grid(BCHUNKS, NSLAB);   // 64 x 36 = 2304 blocks

    // iter 1
    caps_main<1><<<grid, NTHREADS, 0, stream>>>(x, W, bias, v, b2, s_part);
    caps_squash<<<160, 256, 0, stream>>>(s_part, v, L2E);
    // iter 2
    caps_main<2><<<grid, NTHREADS, 0, stream>>>(x, W, bias, v, b2, s_part);
    caps_squash<<<160, 256, 0, stream>>>(s_part, v, L2E);
    // final
    caps_main<3><<<grid, NTHREADS, 0, stream>>>(x, W, bias, v, b2, s_part);
    caps_squash<<<160, 256, 0, stream>>>(s_part, out, 1.0f);
}

// Round 6
// 167.759 us; speedup vs baseline: 1.0735x; 1.0384x over previous
//
#include <hip/hip_runtime.h>
#include <math.h>

// Problem constants
#define BATCH 256
#define IC    1152
#define EDIM  8
#define NC    10
#define DV    16

// Tiling
#define ITILE  8                    // i's covered by thread layout (il = 0..7)
#define NCHUNK 4                    // i-chunks looped per block
#define ITOT   (ITILE * NCHUNK)     // 32 i's per block
#define NB     4                    // b's per block (register s-acc = 20 VGPRs)
#define NTHREADS 256                // 256 = 16 d * 2 il_lo * 2 ch * 4 il_hi
#define NWAVES 4
#define NSLAB  (IC / ITOT)          // 36 partial slabs
#define BCHUNKS (BATCH / NB)        // 64
#define SCD (NC * DV)               // 160
#define SPART_STRIDE (BATCH * SCD)  // 40960 floats per slab
#define L2E 1.4426950408889634f

typedef float v2f __attribute__((ext_vector_type(2)));
typedef float v4f __attribute__((ext_vector_type(4)));

// ---------------------------------------------------------------------------
// DPP-based 16-lane (row) sum reduce — all VALU, no DS pipe.
// MUST stay on __builtin_amdgcn_update_dpp: the compiler inserts the
// mandatory VALU->DPP hazard wait-states. R2's hand-written v_add_f32_dpp
// inline asm skipped them (hazard recognizer doesn't scan asm bodies) and
// silently read stale lanes -> absmax 0.39 FAIL. Do not regress.
// ---------------------------------------------------------------------------
template<int CTRL>
__device__ __forceinline__ float dpp_add(float x) {
    int r = __builtin_amdgcn_update_dpp(0, __float_as_int(x), CTRL, 0xF, 0xF, true);
    return x + __int_as_float(r);
}
__device__ __forceinline__ float row_reduce16(float x) {
    x = dpp_add<0xB1>(x);   // quad_perm [1,0,3,2] : xor 1
    x = dpp_add<0x4E>(x);   // quad_perm [2,3,0,1] : xor 2
    x = dpp_add<0x141>(x);  // row_half_mirror     : xor 4
    x = dpp_add<0x140>(x);  // row_mirror          : xor 8
    return x;
}

// ---------------------------------------------------------------------------
// Cross-half (lane ^ 32) sum, pure VALU on gfx950 (no DS pipe / lgkmcnt).
// r[0]+r[1] == x + partner(x) in every lane. Builtin — HW-verified in R1.
// ---------------------------------------------------------------------------
typedef int int2v __attribute__((ext_vector_type(2)));
#if __has_builtin(__builtin_amdgcn_permlane32_swap)
__device__ __forceinline__ float cross32_sum(float x) {
    int2v r = __builtin_amdgcn_permlane32_swap(__float_as_int(x), __float_as_int(x),
                                               false, false);
    return __int_as_float(r[0]) + __int_as_float(r[1]);
}
#else
__device__ __forceinline__ float cross32_sum(float x) { return x + __shfl_xor(x, 32); }
#endif

#if __has_builtin(__builtin_amdgcn_exp2f)
#define EXP2F(x) __builtin_amdgcn_exp2f(x)
#else
#define EXP2F(x) exp2f(x)
#endif

// ---------------------------------------------------------------------------
// 8-element fp32 dot via packed math: v_pk_fma_f32 (CDNA2+ full-rate
// 2xfp32). 1 pk_mul + 3 pk_fma + 1 add = 5 VALU vs 8 scalar FMAs.
// Pairs are aligned sub-registers of the b128-loaded quads — no repack.
// ---------------------------------------------------------------------------
__device__ __forceinline__ float dot8_pk(v4f w0, v4f w1, v4f x0, v4f x1) {
    v2f a =  __builtin_shufflevector(w0, w0, 0, 1) * __builtin_shufflevector(x0, x0, 0, 1);
    a = __builtin_elementwise_fma(__builtin_shufflevector(w0, w0, 2, 3),
                                  __builtin_shufflevector(x0, x0, 2, 3), a);
    a = __builtin_elementwise_fma(__builtin_shufflevector(w1, w1, 0, 1),
                                  __builtin_shufflevector(x1, x1, 0, 1), a);
    a = __builtin_elementwise_fma(__builtin_shufflevector(w1, w1, 2, 3),
                                  __builtin_shufflevector(x1, x1, 2, 3), a);
    return a[0] + a[1];
}

// ---------------------------------------------------------------------------
// Main fused kernel. LANE MAP: d = bits0-3, il_lo = bit4, ch = bit5,
// il_hi = bits6-7 (== wid). ch at bit5 makes the softmax cross-ch sum a
// v_permlane32_swap (VALU).
//
// STRUCTURE = R3's proven one (169.6 us): slab s-partials written by the
// epilogue (plain stores), reduced+squashed by a separate tiny kernel;
// v staged to LDS in the prologue; bias + b2 accessed from global in the
// body. Structural lessons (do not regress):
//   R1: device-atomic s-accum -> WRITE_SIZE 5.8->23 MB (atomics punch
//       through non-coherent XCD L2s to fabric). REVERTED.
//   R4: LDS-staging b2/bias pushed VGPR 84->88 = occupancy cliff
//       (25->18.5%, +10us). REVERTED.
//   R5: grid(bcb-fast) W-sweep: all resident blocks share one icb and
//       march through W slices in lockstep -> FETCH 20.3->37.2 MB
//       (per-XCD L2 refills), +3us. REVERTED to grid(icb-fast).
//
// R6 change (register-neutral): u_hat dot via v_pk_fma_f32 (dot8_pk).
//
// SPILL/VGPR HISTORY (do not regress):
//   (256,4)/(256,3) caps spilled; (256,2) cap 256 with NB=4 allocates 84
//   VGPR. 85..88+ VGPR drops a wave/SIMD (R4: -17% TLP). Do NOT hoist
//   v/b2/bias into registers or add prologue staging arrays.
//
// NUMERICS: softmax max-pass removed (|logits| <~ 20 << 88; R1/R3-proven).
// 1/sum via v_rcp_f32 (rel err ~1e-7). Routing logits in log2 domain:
// v_in pre-scaled by L2E (caps_squash writes it), bias scaled once per
// i-chunk, so softmax exp is raw v_exp_f32 (exp2). b2 stores scaled
// logits (internal-only buffer, consistent between MODE 2 and 3).
//
// MODE 1: c = softmax(bias)                              -> s1 partials
// MODE 2: b2 = L2E*(u.v1) + 2*L2E*bias (stored), softmax -> s2 partials
// MODE 3: b3 = L2E*(u.v2) + b2 + L2E*bias, softmax       -> s3 partials
// ---------------------------------------------------------------------------
template<int MODE>
__global__ __launch_bounds__(NTHREADS, 2)
void caps_main(const float* __restrict__ x,
               const float* __restrict__ W,
               const float* __restrict__ bias,
               const float* __restrict__ v_in,   // pre-scaled by L2E
               float* __restrict__ b2,
               float* __restrict__ s_part)
{
    __shared__ float sx[NB][ITOT * EDIM];    // 4 KB
    __shared__ float swv[NWAVES][NB][SCD];   // 10 KB — wave-private slabs
    __shared__ float vls[NB][SCD];           // 2.5 KB — v tile (MODE != 1)

    const int tid = threadIdx.x;
    const int d   = tid & 15;
    const int ch  = (tid >> 5) & 1;                       // lane bit 5
    const int il  = ((tid >> 4) & 1) | (((tid >> 6) & 3) << 1);
    const int wid = tid >> 6;                // 0..3
    const int icb = blockIdx.x;              // 0..35  (fast axis — R5 lesson)
    const int bcb = blockIdx.y;              // 0..63
    const int i0  = icb * ITOT;
    const int b0  = bcb * NB;

    // ---- stage x slice: 256 float4, one per thread, coalesced ----
    {
        const float4* xg = (const float4*)x;
        float4* xs = (float4*)&sx[0][0];
        int bb = tid >> 6;                   // 64 float4 per b row
        int w  = tid & 63;
        xs[tid] = xg[(size_t)(b0 + bb) * (IC * EDIM / 4) + i0 * (EDIM / 4) + w];
    }
    // ---- stage v tile (640 floats, coalesced) ----
    if (MODE != 1) {
        #pragma unroll
        for (int t = 0; t < 3; ++t) {
            int j = t * NTHREADS + tid;
            if (j < NB * SCD)
                (&vls[0][0])[j] = v_in[(size_t)b0 * SCD + j];
        }
    }

    float sacc[NB][5];
    #pragma unroll
    for (int bb = 0; bb < NB; ++bb)
        #pragma unroll
        for (int k = 0; k < 5; ++k) sacc[bb][k] = 0.f;

    __syncthreads();

    const v4f* Wg = (const v4f*)W;

    #pragma unroll 1
    for (int ic = 0; ic < NCHUNK; ++ic) {
        const int i = i0 + ic * ITILE + il;

        // W fragment + bias for this i-chunk
        v4f   w4[5][2];
        float bv[5];
        #pragma unroll
        for (int k = 0; k < 5; ++k) {
            int c = ch * 5 + k;
            size_t base = ((size_t)(i * NC + c) * DV + d) * 2;
            w4[k][0] = Wg[base];
            w4[k][1] = Wg[base + 1];
            bv[k]    = bias[i * NC + c];
        }

        float cw[5];
        float bvs[5];
        if (MODE == 1) {
            // softmax(bias[i,:]) — batch-independent, once per i-chunk
            float ssum = 0.f, ex[5];
            #pragma unroll
            for (int k = 0; k < 5; ++k) { ex[k] = __expf(bv[k]); ssum += ex[k]; }
            ssum = cross32_sum(ssum);
            float inv = __builtin_amdgcn_rcpf(ssum);
            #pragma unroll
            for (int k = 0; k < 5; ++k) cw[k] = ex[k] * inv;
        } else {
            #pragma unroll
            for (int k = 0; k < 5; ++k) bvs[k] = bv[k] * L2E;
        }

        #pragma unroll
        for (int bb = 0; bb < NB; ++bb) {
            const int b = b0 + bb;
            const v4f x0 = ((const v4f*)&sx[bb][(ic * ITILE + il) * EDIM])[0];
            const v4f x1 = ((const v4f*)&sx[bb][(ic * ITILE + il) * EDIM])[1];

            // u_hat[b, i, c_k, d] — packed-pair dot (v_pk_fma_f32)
            float u[5];
            #pragma unroll
            for (int k = 0; k < 5; ++k)
                u[k] = dot8_pk(w4[k][0], w4[k][1], x0, x1);

            if (MODE != 1) {
                // agreement (L2E-scaled via v): sum over d via DPP row reduce
                const float* vb = &vls[bb][ch * 80 + d];
                float t[5];
                #pragma unroll
                for (int k = 0; k < 5; ++k) t[k] = u[k] * vb[k * 16];
                #pragma unroll
                for (int k = 0; k < 5; ++k) t[k] = row_reduce16(t[k]);

                float br[5];
                float* bp = b2 + (((size_t)b * IC + i) * 2 + ch) * 8;  // padded
                if (MODE == 2) {
                    #pragma unroll
                    for (int k = 0; k < 5; ++k) br[k] = fmaf(2.0f, bvs[k], t[k]);
                    if (d == 0) {
                        #pragma unroll
                        for (int k = 0; k < 5; ++k) bp[k] = br[k];
                    }
                } else {
                    #pragma unroll
                    for (int k = 0; k < 5; ++k) br[k] = t[k] + bp[k] + bvs[k];
                }
                // softmax over 10 c's: 5 local + partner half via permlane32.
                // Logits are log2-domain -> raw v_exp_f32, no max-pass.
                float ssum = 0.f, ex[5];
                #pragma unroll
                for (int k = 0; k < 5; ++k) { ex[k] = EXP2F(br[k]); ssum += ex[k]; }
                ssum = cross32_sum(ssum);
                float inv = __builtin_amdgcn_rcpf(ssum);
                #pragma unroll
                for (int k = 0; k < 5; ++k) cw[k] = ex[k] * inv;
            }

            // register s-accumulation — no LDS, no shuffle, no barrier
            #pragma unroll
            for (int k = 0; k < 5; ++k)
                sacc[bb][k] = fmaf(cw[k], u[k], sacc[bb][k]);
        }
    }

    // ---- epilogue: il-pair reduce + wave slabs + 4-way reduce + flush ----
    #pragma unroll
    for (int bb = 0; bb < NB; ++bb) {
        #pragma unroll
        for (int k = 0; k < 5; ++k) {
            float s = sacc[bb][k] + __shfl_xor(sacc[bb][k], 16);
            if ((tid & 16) == 0)
                swv[wid][bb][ch * 80 + k * 16 + d] = s;
        }
    }
    __syncthreads();
    for (int j = tid; j < NB * SCD; j += NTHREADS) {    // 640 elems
        int bb = j / SCD;
        int cd = j - bb * SCD;
        float s = (swv[0][bb][cd] + swv[1][bb][cd])
                + (swv[2][bb][cd] + swv[3][bb][cd]);
        s_part[((size_t)icb * BATCH + b0 + bb) * SCD + cd] = s;
    }
}

// ---------------------------------------------------------------------------
// Reduce s-partials over the 36 slabs and apply squash.
// Block = 16 (b,c) groups x 16 d. Grid = 2560/16 = 160 blocks.
// mult = L2E for intermediate v (log2-domain routing), 1.0 for final out.
// ---------------------------------------------------------------------------
__global__ __launch_bounds__(256)
void caps_squash(const float* __restrict__ s_part, float* __restrict__ out,
                 float mult)
{
    const int tid = threadIdx.x;
    const int bc  = blockIdx.x * 16 + (tid >> 4);
    const size_t off = (size_t)bc * DV + (tid & 15);

    float a[4] = {0.f, 0.f, 0.f, 0.f};
    #pragma unroll
    for (int ic = 0; ic < NSLAB; ic += 4) {
        #pragma unroll
        for (int j = 0; j < 4; ++j)
            a[j] += s_part[(size_t)(ic + j) * SPART_STRIDE + off];
    }
    float s = (a[0] + a[1]) + (a[2] + a[3]);

    float sq = row_reduce16(s * s);

    // scale = sq/(1+sq)/sqrt(sq+EPS), EPS = 1e-7 (matches reference)
    float scale = sq / ((1.0f + sq) * sqrtf(sq + 1e-7f));
    out[off] = (mult * scale) * s;
}

// ---------------------------------------------------------------------------
extern "C" void kernel_launch(void* const* d_in, const int* in_sizes, int n_in,
                              void* d_out, int out_size, void* d_ws, size_t ws_size,
                              hipStream_t stream)
{
    const float* x    = (const float*)d_in[0];   // [256,1152,8]
    const float* W    = (const float*)d_in[1];   // [1152,10,16,8]
    const float* bias = (const float*)d_in[2];   // [1152,10]
    float* out = (float*)d_out;                  // [256,10,16]

    float* ws     = (float*)d_ws;
    float* s_part = ws;                                       // 36*40960 = 1,474,560 f
    float* v      = s_part + (size_t)NSLAB * SPART_STRIDE;    // 40,960 f (L2E-scaled)
    float* b2     = v + SPART_STRIDE;                         // padded: 4,718,592 f
    // total ws use: ~25 MB

    // icb on the FAST grid axis (R3 order) — R5's bcb-fast variant caused a
    // lockstep W-slice sweep and +17 MB of L2 refill traffic. Keep icb-fast.
    dim3 grid(NSLAB, BCHUNKS);   // 36 x 64 = 2304 blocks

    // iter 1
    caps_main<1><<<grid, NTHREADS, 0, stream>>>(x, W, bias, v, b2, s_part);
    caps_squash<<<160, 256, 0, stream>>>(s_part, v, L2E);
    // iter 2
    caps_main<2><<<grid, NTHREADS, 0, stream>>>(x, W, bias, v, b2, s_part);
    caps_squash<<<160, 256, 0, stream>>>(s_part, v, L2E);
    // final
    caps_main<3><<<grid, NTHREADS, 0, stream>>>(x, W, bias, v, b2, s_part);
    caps_squash<<<160, 256, 0, stream>>>(s_part, out, 1.0f);
}